// Round 7
// baseline (497.840 us; speedup 1.0000x reference)
//
#include <hip/hip_runtime.h>

#define NN 50000
#define NE 800000
#define CC 128
#define SLAB (NN * CC)
#define BN_EPS 1e-5f

typedef __attribute__((ext_vector_type(8))) short bf16x8;
typedef __attribute__((ext_vector_type(4))) float f32x4;
typedef unsigned short ushort_t;

__device__ inline ushort_t f2bf(float v) {
  unsigned u = __builtin_bit_cast(unsigned, v);
  unsigned r = u + 0x7FFFu + ((u >> 16) & 1u);
  return (ushort_t)(r >> 16);
}
__device__ inline float bf2f(unsigned hi16_lo) {  // low 16 bits hold bf16
  return __builtin_bit_cast(float, hi16_lo << 16);
}

// ---------------- utility ----------------
__global__ void zero_int_kernel(int* __restrict__ p, int n) {
  int i = blockIdx.x * blockDim.x + threadIdx.x;
  if (i < n) p[i] = 0;
}

// ---------------- CSR build ----------------
__global__ void count_kernel(const int* __restrict__ dst, int* __restrict__ counts) {
  int e = blockIdx.x * blockDim.x + threadIdx.x;
  if (e < NE) atomicAdd(&counts[dst[e]], 1);
}

__global__ void scan1_kernel(const int* __restrict__ counts, int* __restrict__ excl,
                             int* __restrict__ blocksum) {
  __shared__ int s[256];
  int t = threadIdx.x;
  int i = blockIdx.x * 256 + t;
  int v = (i < NN) ? counts[i] : 0;
  s[t] = v;
  for (int off = 1; off < 256; off <<= 1) {
    __syncthreads();
    int add = (t >= off) ? s[t - off] : 0;
    __syncthreads();
    s[t] += add;
  }
  __syncthreads();
  if (i < NN) excl[i] = s[t] - v;
  if (t == 255) blocksum[blockIdx.x] = s[255];
}

__global__ void scan2_kernel(int* __restrict__ blocksum, int nb) {
  __shared__ int s[256];
  int t = threadIdx.x;
  int v = (t < nb) ? blocksum[t] : 0;
  s[t] = v;
  for (int off = 1; off < 256; off <<= 1) {
    __syncthreads();
    int add = (t >= off) ? s[t - off] : 0;
    __syncthreads();
    s[t] += add;
  }
  __syncthreads();
  if (t < nb) blocksum[t] = s[t] - v;
}

__global__ void scan3_kernel(int* __restrict__ excl, const int* __restrict__ blocksum) {
  int i = blockIdx.x * 256 + threadIdx.x;
  if (i < NN) excl[i] += blocksum[blockIdx.x];
}

__global__ void fill_kernel(const int* __restrict__ src, const int* __restrict__ dst,
                            const int* __restrict__ starts, int* __restrict__ fill,
                            int* __restrict__ bucket) {
  int e = blockIdx.x * blockDim.x + threadIdx.x;
  if (e < NE) {
    int d = dst[e];
    int pos = atomicAdd(&fill[d], 1);
    bucket[starts[d] + pos] = src[e];
  }
}

// ---------------- W prep: split + pack into per-(ks,nt) 64-lane fragments ----------------
// Wp[(ks*8+nt)*512 + l*8 + j] == W[k][n], n = nt*16+(l&15), k = ks*32+(l>>4)*8+j
__global__ void prep_w_kernel(const float* __restrict__ fh_W, const float* __restrict__ W1,
                              const float* __restrict__ W2, short* __restrict__ whi,
                              short* __restrict__ wlo) {
  int m = blockIdx.x;
  const float* src = (m == 0) ? fh_W : ((m <= 3) ? W1 + (m - 1) * CC * CC : W2 + (m - 4) * CC * CC);
  short* hi = whi + m * CC * CC;
  short* lo = wlo + m * CC * CC;
  for (int it = 0; it < 64; ++it) {
    int idx = it * 256 + threadIdx.x;  // 0..16383
    int j = idx & 7;
    int l = (idx >> 3) & 63;
    int nt = (idx >> 9) & 7;
    int ks = idx >> 12;
    int n = nt * 16 + (l & 15);
    int k = ks * 32 + ((l >> 4) << 3) + j;
    float v = src[k * CC + n];
    unsigned u = __builtin_bit_cast(unsigned, v);
    unsigned short h = (unsigned short)(u >> 16);
    float hf = __builtin_bit_cast(float, ((unsigned)h) << 16);
    float r = v - hf;
    unsigned ur = __builtin_bit_cast(unsigned, r);
    hi[idx] = (short)h;
    lo[idx] = (short)(ur >> 16);
  }
}

// ---------------- GEMM0 (no LDS): out = x @ fh_W + b (fp32 A, 3-MFMA split) ----------------
__global__ __launch_bounds__(256) void gemm0_kernel(
    const float* __restrict__ A, const short* __restrict__ Wp_hi, const short* __restrict__ Wp_lo,
    const float* __restrict__ bias, float* __restrict__ out, ushort_t* __restrict__ h16) {
  const int t = threadIdx.x;
  const int l = t & 63;
  const int wv = t >> 6;
  const int m0 = blockIdx.x * 64 + wv * 16;
  const int row = m0 + (l & 15);
  const int kg = (l >> 4) * 8;

  f32x4 acc[8];
#pragma unroll
  for (int i = 0; i < 8; ++i) acc[i] = (f32x4){0.f, 0.f, 0.f, 0.f};

#pragma unroll
  for (int ks = 0; ks < 4; ++ks) {
    float av[8];
    if (row < NN) {
      const float* ap = &A[row * CC + ks * 32 + kg];
      float4 v0 = *(const float4*)ap;
      float4 v1 = *(const float4*)(ap + 4);
      av[0] = v0.x; av[1] = v0.y; av[2] = v0.z; av[3] = v0.w;
      av[4] = v1.x; av[5] = v1.y; av[6] = v1.z; av[7] = v1.w;
    } else {
#pragma unroll
      for (int i = 0; i < 8; ++i) av[i] = 0.f;
    }
    bf16x8 ah, al;
#pragma unroll
    for (int i = 0; i < 8; ++i) {
      unsigned u = __builtin_bit_cast(unsigned, av[i]);
      unsigned short hbits = (unsigned short)(u >> 16);
      float hf = __builtin_bit_cast(float, ((unsigned)hbits) << 16);
      float r = av[i] - hf;
      unsigned ur = __builtin_bit_cast(unsigned, r);
      ah[i] = (short)hbits;
      al[i] = (short)(ur >> 16);
    }
#pragma unroll
    for (int nt = 0; nt < 8; ++nt) {
      const int base = (ks * 8 + nt) * 512 + l * 8;
      bf16x8 wh = *(const bf16x8*)&Wp_hi[base];
      bf16x8 wl = *(const bf16x8*)&Wp_lo[base];
      acc[nt] = __builtin_amdgcn_mfma_f32_16x16x32_bf16(ah, wh, acc[nt], 0, 0, 0);
      acc[nt] = __builtin_amdgcn_mfma_f32_16x16x32_bf16(al, wh, acc[nt], 0, 0, 0);
      acc[nt] = __builtin_amdgcn_mfma_f32_16x16x32_bf16(ah, wl, acc[nt], 0, 0, 0);
    }
  }

  const int rbase = m0 + (l >> 4) * 4;
  const int cn = l & 15;
#pragma unroll
  for (int nt = 0; nt < 8; ++nt) {
    int c = nt * 16 + cn;
    float bv = bias[c];
#pragma unroll
    for (int r = 0; r < 4; ++r) {
      int rr = rbase + r;
      if (rr < NN) {
        float v = acc[nt][r] + bv;
        out[rr * CC + c] = v;
        h16[rr * CC + c] = f2bf(v);
      }
    }
  }
}

// ---------------- fused gather + GEMM1: tmp16 = bf16((h+sum_nb h) @ W1 + b1), stats1 ----------------
// Each wave gathers its 16 rows into a swizzled LDS bf16 tile, then MFMAs from LDS.
__global__ __launch_bounds__(256) void fused1_kernel(
    const ushort_t* __restrict__ h16, const int* __restrict__ starts,
    const int* __restrict__ counts, const int* __restrict__ bucket,
    const short* __restrict__ Wp_hi, const short* __restrict__ Wp_lo,
    const float* __restrict__ bias, ushort_t* __restrict__ tmp16,
    float* __restrict__ stats_out) {
  __shared__ ushort_t tile[4][16][128];  // [wave][row][chan], byte-swizzled within row
  __shared__ float sred[2 * CC];
  const int t = threadIdx.x;
  const int l = t & 63;
  const int wv = t >> 6;
  const int q = l >> 4;
  const int j16 = l & 15;
  const int m0 = blockIdx.x * 64 + wv * 16;
  sred[t] = 0.f;

  const uint4* tbl = (const uint4*)h16;

  // ---- gather phase: 16 nodes per wave, 4 neighbors/step, 4-deep unroll ----
  for (int j = 0; j < 16; ++j) {
    const int node = m0 + j;
    float acc[8];
#pragma unroll
    for (int k = 0; k < 8; ++k) acc[k] = 0.f;
    if (node < NN) {
      if (q == 0) {
        uint4 u = tbl[node * 16 + j16];
        acc[0] = bf2f(u.x & 0xFFFF); acc[1] = bf2f(u.x >> 16);
        acc[2] = bf2f(u.y & 0xFFFF); acc[3] = bf2f(u.y >> 16);
        acc[4] = bf2f(u.z & 0xFFFF); acc[5] = bf2f(u.z >> 16);
        acc[6] = bf2f(u.w & 0xFFFF); acc[7] = bf2f(u.w >> 16);
      }
      const int s = starts[node];
      const int n = counts[node];
      for (int base = 0; base < n; base += 64) {
        int nb = min(n - base, 64);
        int idx = (l < nb) ? bucket[s + base + l] : 0;
        int jj = 0;
        for (; jj + 16 <= nb; jj += 16) {
          int sr0 = __shfl(idx, jj + q);
          int sr1 = __shfl(idx, jj + 4 + q);
          int sr2 = __shfl(idx, jj + 8 + q);
          int sr3 = __shfl(idx, jj + 12 + q);
          uint4 a = tbl[sr0 * 16 + j16];
          uint4 b = tbl[sr1 * 16 + j16];
          uint4 cc2 = tbl[sr2 * 16 + j16];
          uint4 d = tbl[sr3 * 16 + j16];
          acc[0] += bf2f(a.x & 0xFFFF) + bf2f(b.x & 0xFFFF) + bf2f(cc2.x & 0xFFFF) + bf2f(d.x & 0xFFFF);
          acc[1] += bf2f(a.x >> 16) + bf2f(b.x >> 16) + bf2f(cc2.x >> 16) + bf2f(d.x >> 16);
          acc[2] += bf2f(a.y & 0xFFFF) + bf2f(b.y & 0xFFFF) + bf2f(cc2.y & 0xFFFF) + bf2f(d.y & 0xFFFF);
          acc[3] += bf2f(a.y >> 16) + bf2f(b.y >> 16) + bf2f(cc2.y >> 16) + bf2f(d.y >> 16);
          acc[4] += bf2f(a.z & 0xFFFF) + bf2f(b.z & 0xFFFF) + bf2f(cc2.z & 0xFFFF) + bf2f(d.z & 0xFFFF);
          acc[5] += bf2f(a.z >> 16) + bf2f(b.z >> 16) + bf2f(cc2.z >> 16) + bf2f(d.z >> 16);
          acc[6] += bf2f(a.w & 0xFFFF) + bf2f(b.w & 0xFFFF) + bf2f(cc2.w & 0xFFFF) + bf2f(d.w & 0xFFFF);
          acc[7] += bf2f(a.w >> 16) + bf2f(b.w >> 16) + bf2f(cc2.w >> 16) + bf2f(d.w >> 16);
        }
        for (; jj < nb; jj += 4) {
          int i = jj + q;
          int sr = __shfl(idx, (i < nb) ? i : (nb - 1));
          if (i < nb) {
            uint4 a = tbl[sr * 16 + j16];
            acc[0] += bf2f(a.x & 0xFFFF); acc[1] += bf2f(a.x >> 16);
            acc[2] += bf2f(a.y & 0xFFFF); acc[3] += bf2f(a.y >> 16);
            acc[4] += bf2f(a.z & 0xFFFF); acc[5] += bf2f(a.z >> 16);
            acc[6] += bf2f(a.w & 0xFFFF); acc[7] += bf2f(a.w >> 16);
          }
        }
      }
#pragma unroll
      for (int k = 0; k < 8; ++k) {
        acc[k] += __shfl_xor(acc[k], 16);
        acc[k] += __shfl_xor(acc[k], 32);
      }
    }
    if (q == 0) {
      uint4 o;
      o.x = (unsigned)f2bf(acc[0]) | ((unsigned)f2bf(acc[1]) << 16);
      o.y = (unsigned)f2bf(acc[2]) | ((unsigned)f2bf(acc[3]) << 16);
      o.z = (unsigned)f2bf(acc[4]) | ((unsigned)f2bf(acc[5]) << 16);
      o.w = (unsigned)f2bf(acc[6]) | ((unsigned)f2bf(acc[7]) << 16);
      int byteoff = (j16 * 16) ^ ((j & 7) << 4);
      *(uint4*)((char*)&tile[wv][j][0] + byteoff) = o;
    }
  }
  __syncthreads();

  // ---- MFMA phase ----
  f32x4 acc2[8];
#pragma unroll
  for (int i = 0; i < 8; ++i) acc2[i] = (f32x4){0.f, 0.f, 0.f, 0.f};

#pragma unroll
  for (int ks = 0; ks < 4; ++ks) {
    int byteoff = ((ks * 4 + q) * 16) ^ ((j16 & 7) << 4);
    bf16x8 ah = *(const bf16x8*)((const char*)&tile[wv][j16][0] + byteoff);
#pragma unroll
    for (int nt = 0; nt < 8; ++nt) {
      const int base = (ks * 8 + nt) * 512 + l * 8;
      bf16x8 wh = *(const bf16x8*)&Wp_hi[base];
      bf16x8 wl = *(const bf16x8*)&Wp_lo[base];
      acc2[nt] = __builtin_amdgcn_mfma_f32_16x16x32_bf16(ah, wh, acc2[nt], 0, 0, 0);
      acc2[nt] = __builtin_amdgcn_mfma_f32_16x16x32_bf16(ah, wl, acc2[nt], 0, 0, 0);
    }
  }

  // epilogue: bias, bf16 store, stats
  const int rbase = m0 + (l >> 4) * 4;
  const int cn = l & 15;
#pragma unroll
  for (int nt = 0; nt < 8; ++nt) {
    int c = nt * 16 + cn;
    float bv = bias[c];
    float s = 0.f, qq = 0.f;
#pragma unroll
    for (int r = 0; r < 4; ++r) {
      int rr = rbase + r;
      if (rr < NN) {
        float v = acc2[nt][r] + bv;
        tmp16[rr * CC + c] = f2bf(v);
        s += v; qq += v * v;
      }
    }
    s += __shfl_xor(s, 16); s += __shfl_xor(s, 32);
    qq += __shfl_xor(qq, 16); qq += __shfl_xor(qq, 32);
    if (q == 0) {
      atomicAdd(&sred[c], s);
      atomicAdd(&sred[CC + c], qq);
    }
  }
  __syncthreads();
  atomicAdd(&stats_out[t], sred[t]);
}

// ---------------- GEMM2: tmp2 = relu(BN1(tmp16)) @ W2 + b2 (fp32 out), stats2 ----------------
__global__ __launch_bounds__(256) void gemm2_kernel(
    const ushort_t* __restrict__ tmp16, const short* __restrict__ Wp_hi,
    const short* __restrict__ Wp_lo, const float* __restrict__ bias,
    const float* __restrict__ stats_in, const float* __restrict__ g,
    const float* __restrict__ be, float* __restrict__ tmp2, float* __restrict__ stats_out) {
  __shared__ float sred[2 * CC];
  const int t = threadIdx.x;
  const int l = t & 63;
  const int wv = t >> 6;
  const int m0 = blockIdx.x * 64 + wv * 16;
  const int row = m0 + (l & 15);
  const int kg = (l >> 4) * 8;
  sred[t] = 0.f;

  // BN1 coefficients for this lane's 4x8 channels (ks-major)
  f32x4 acc[8];
#pragma unroll
  for (int i = 0; i < 8; ++i) acc[i] = (f32x4){0.f, 0.f, 0.f, 0.f};

#pragma unroll
  for (int ks = 0; ks < 4; ++ks) {
    bf16x8 ah;
    if (row < NN) {
      bf16x8 raw = *(const bf16x8*)&tmp16[row * CC + ks * 32 + kg];
#pragma unroll
      for (int i = 0; i < 8; ++i) {
        int c = ks * 32 + kg + i;
        float mu = stats_in[c] * (1.0f / NN);
        float var = fmaxf(stats_in[CC + c] * (1.0f / NN) - mu * mu, 0.f);
        float a = g[c] * rsqrtf(var + BN_EPS);
        float d = fmaf(-mu, a, be[c]);
        float v = bf2f((unsigned)(ushort_t)raw[i]);
        v = fmaxf(fmaf(v, a, d), 0.f);
        ah[i] = (short)f2bf(v);
      }
    } else {
#pragma unroll
      for (int i = 0; i < 8; ++i) ah[i] = 0;
    }
#pragma unroll
    for (int nt = 0; nt < 8; ++nt) {
      const int base = (ks * 8 + nt) * 512 + l * 8;
      bf16x8 wh = *(const bf16x8*)&Wp_hi[base];
      bf16x8 wl = *(const bf16x8*)&Wp_lo[base];
      acc[nt] = __builtin_amdgcn_mfma_f32_16x16x32_bf16(ah, wh, acc[nt], 0, 0, 0);
      acc[nt] = __builtin_amdgcn_mfma_f32_16x16x32_bf16(ah, wl, acc[nt], 0, 0, 0);
    }
  }

  __syncthreads();
  const int rbase = m0 + (l >> 4) * 4;
  const int cn = l & 15;
#pragma unroll
  for (int nt = 0; nt < 8; ++nt) {
    int c = nt * 16 + cn;
    float bv = bias[c];
    float s = 0.f, qq = 0.f;
#pragma unroll
    for (int r = 0; r < 4; ++r) {
      int rr = rbase + r;
      if (rr < NN) {
        float v = acc[nt][r] + bv;
        tmp2[rr * CC + c] = v;
        s += v; qq += v * v;
      }
    }
    s += __shfl_xor(s, 16); s += __shfl_xor(s, 32);
    qq += __shfl_xor(qq, 16); qq += __shfl_xor(qq, 32);
    if ((l >> 4) == 0) {
      atomicAdd(&sred[c], s);
      atomicAdd(&sred[CC + c], qq);
    }
  }
  __syncthreads();
  atomicAdd(&stats_out[t], sred[t]);
}

// ---------------- BN2(inline) + relu apply -> out slab (+ bf16 table) ----------------
__global__ void apply_kernel(const float* __restrict__ tmp, const float* __restrict__ stats2,
                             const float* __restrict__ g2, const float* __restrict__ be2,
                             float* __restrict__ outslab, ushort_t* __restrict__ h16) {
  int i = blockIdx.x * blockDim.x + threadIdx.x;  // float4 index
  float4 v = ((const float4*)tmp)[i];
  int c = (i & 31) << 2;
  float4 sm = *(const float4*)&stats2[c];
  float4 sq = *(const float4*)&stats2[CC + c];
  float4 gg = *(const float4*)&g2[c];
  float4 bb = *(const float4*)&be2[c];
  float4 a, d;
  {
    float mu = sm.x * (1.0f / NN), var = fmaxf(sq.x * (1.0f / NN) - mu * mu, 0.f);
    a.x = gg.x * rsqrtf(var + BN_EPS); d.x = fmaf(-mu, a.x, bb.x);
    mu = sm.y * (1.0f / NN); var = fmaxf(sq.y * (1.0f / NN) - mu * mu, 0.f);
    a.y = gg.y * rsqrtf(var + BN_EPS); d.y = fmaf(-mu, a.y, bb.y);
    mu = sm.z * (1.0f / NN); var = fmaxf(sq.z * (1.0f / NN) - mu * mu, 0.f);
    a.z = gg.z * rsqrtf(var + BN_EPS); d.z = fmaf(-mu, a.z, bb.z);
    mu = sm.w * (1.0f / NN); var = fmaxf(sq.w * (1.0f / NN) - mu * mu, 0.f);
    a.w = gg.w * rsqrtf(var + BN_EPS); d.w = fmaf(-mu, a.w, bb.w);
  }
  v.x = fmaxf(fmaf(v.x, a.x, d.x), 0.f);
  v.y = fmaxf(fmaf(v.y, a.y, d.y), 0.f);
  v.z = fmaxf(fmaf(v.z, a.z, d.z), 0.f);
  v.w = fmaxf(fmaf(v.w, a.w, d.w), 0.f);
  ((float4*)outslab)[i] = v;
  if (h16) {
    ushort_t p[4] = {f2bf(v.x), f2bf(v.y), f2bf(v.z), f2bf(v.w)};
    *(uint2*)&h16[i * 4] = *(uint2*)p;
  }
}

// ---------------- launch ----------------
extern "C" void kernel_launch(void* const* d_in, const int* in_sizes, int n_in,
                              void* d_out, int out_size, void* d_ws, size_t ws_size,
                              hipStream_t stream) {
  const float* x    = (const float*)d_in[0];
  const int*   edge = (const int*)d_in[1];
  const float* fh_W = (const float*)d_in[3];
  const float* fh_b = (const float*)d_in[4];
  const float* W1   = (const float*)d_in[5];
  const float* b1   = (const float*)d_in[6];
  const float* g1   = (const float*)d_in[7];
  const float* be1  = (const float*)d_in[8];
  const float* W2   = (const float*)d_in[9];
  const float* b2   = (const float*)d_in[10];
  const float* g2   = (const float*)d_in[11];
  const float* be2  = (const float*)d_in[12];
  float* out = (float*)d_out;

  const int* src = edge;
  const int* dst = edge + NE;

  // workspace layout: [counts 50048][fill 50048][stats 1536] all zeroed together
  int* counts   = (int*)d_ws;
  int* fill     = counts + 50048;
  float* stats  = (float*)(fill + 50048);      // 6 x 256 floats
  int* starts   = (int*)(stats + 1536);        // 50048
  int* blocksum = starts + 50048;              // 256
  int* bucket   = blocksum + 256;              // 800000
  short* whi    = (short*)(bucket + NE);       // 7*16384 packed hi
  short* wlo    = whi + 7 * CC * CC;           // 7*16384 packed lo
  ushort_t* h16 = (ushort_t*)(wlo + 7 * CC * CC);  // SLAB bf16
  ushort_t* tmp16 = h16 + SLAB;                    // SLAB bf16
  float* tmp2   = (float*)(tmp16 + SLAB);          // SLAB fp32

  // CSR build + stats zero
  zero_int_kernel<<<(101632 + 255) / 256, 256, 0, stream>>>(counts, 101632);
  count_kernel<<<NE / 256, 256, 0, stream>>>(dst, counts);
  scan1_kernel<<<196, 256, 0, stream>>>(counts, starts, blocksum);
  scan2_kernel<<<1, 256, 0, stream>>>(blocksum, 196);
  scan3_kernel<<<196, 256, 0, stream>>>(starts, blocksum);
  fill_kernel<<<NE / 256, 256, 0, stream>>>(src, dst, starts, fill, bucket);

  // weight prep (packed fragments)
  prep_w_kernel<<<7, 256, 0, stream>>>(fh_W, W1, W2, whi, wlo);

  // first head: out slab 0 = x @ fh_W + fh_b (+ h16 table)
  gemm0_kernel<<<782, 256, 0, stream>>>(x, whi, wlo, fh_b, out, h16);

  for (int ly = 0; ly < 3; ++ly) {
    float* stats1 = stats + (ly * 2) * 256;
    float* stats2 = stats + (ly * 2 + 1) * 256;
    fused1_kernel<<<782, 256, 0, stream>>>(
        h16, starts, counts, bucket, whi + (1 + ly) * CC * CC, wlo + (1 + ly) * CC * CC,
        b1 + ly * CC, tmp16, stats1);
    gemm2_kernel<<<782, 256, 0, stream>>>(
        tmp16, whi + (4 + ly) * CC * CC, wlo + (4 + ly) * CC * CC, b2 + ly * CC,
        stats1, g1 + ly * CC, be1 + ly * CC, tmp2, stats2);
    apply_kernel<<<SLAB / 4 / 256, 256, 0, stream>>>(
        tmp2, stats2, g2 + ly * CC, be2 + ly * CC, out + (ly + 1) * SLAB,
        (ly < 2) ? h16 : (ushort_t*)nullptr);
  }
}